// Round 1
// baseline (380.920 us; speedup 1.0000x reference)
//
#include <hip/hip_runtime.h>

// Problem constants
// embedding: (32, 512, 32, 32) f32 ; pixel_shuffle r=4 -> x_ps (32, 32, 128, 128)
// conv 3x3 pad1 (32->32) + BN + ReLU ; head: 32->4 relu -> 1 ; sigmoid
// concat [sig, mask] -> 5x5 conv pad2 (2->1) ; out (32,1,128,128) f32

__global__ __launch_bounds__(256) void fused_main_kernel(
    const float* __restrict__ emb,      // (32,512,32,32)
    const float* __restrict__ inc,      // (32,137)
    const float* __restrict__ conv_w,   // (32,32,3,3) OIHW
    const float* __restrict__ conv_b,   // (32)
    const float* __restrict__ bn_gamma,
    const float* __restrict__ bn_beta,
    const float* __restrict__ bn_mean,
    const float* __restrict__ bn_var,
    float* __restrict__ sig_out)        // (32,128,128)
{
    __shared__ float lw[9216];        // [c*9 + ky*3+kx][oc] : 36 KB
    __shared__ float lx[32 * 324];    // [c][yy*18+xx] halo tile : 41.5 KB
    __shared__ float lhead[137];
    __shared__ float lA[32], lB[32];  // folded BN: v = acc*A + B

    const int tid  = threadIdx.x;
    const int n    = blockIdx.x >> 6;   // 64 tiles per batch image
    const int tile = blockIdx.x & 63;
    const int h0   = (tile >> 3) << 4;
    const int w0   = (tile & 7) << 4;

    // Stage conv weights, reorganized so oc is contiguous:
    // lw[r*32 + oc] = conv_w[oc*288 + r],  r = (c*3+ky)*3+kx
    for (int j = tid; j < 9216; j += 256) {
        int oc = j & 31;
        int r  = j >> 5;
        lw[j] = conv_w[oc * 288 + r];
    }
    // Head params for this group (g == n since NI==1)
    if (tid < 137) lhead[tid] = inc[n * 137 + tid];
    // Fold conv bias + BN into scale/shift
    if (tid < 32) {
        float sc = bn_gamma[tid] * rsqrtf(bn_var[tid] + 1e-5f);
        lA[tid] = sc;
        lB[tid] = (conv_b[tid] - bn_mean[tid]) * sc + bn_beta[tid];
    }
    // Stage pixel-shuffled input tile with halo 1 (zero padded at image edge).
    // x_ps[n,c,H,W] = emb[n, c*16 + (H&3)*4 + (W&3), H>>2, W>>2]
    for (int i = tid; i < 10368; i += 256) {
        int c  = i / 324;
        int r  = i - c * 324;
        int yy = r / 18;
        int xx = r - yy * 18;
        int h  = h0 + yy - 1;
        int w  = w0 + xx - 1;
        float v = 0.0f;
        if ((unsigned)h < 128u && (unsigned)w < 128u) {
            int cc = (c << 4) + ((h & 3) << 2) + (w & 3);
            v = emb[((n * 512 + cc) << 10) + ((h >> 2) << 5) + (w >> 2)];
        }
        lx[i] = v;
    }
    __syncthreads();

    const int tx = tid & 15;
    const int ty = tid >> 4;

    float acc[32];
    #pragma unroll
    for (int o = 0; o < 32; ++o) acc[o] = 0.0f;

    for (int c = 0; c < 32; ++c) {
        const float* lxc = &lx[c * 324 + ty * 18 + tx];
        float xv[9];
        #pragma unroll
        for (int dy = 0; dy < 3; ++dy) {
            #pragma unroll
            for (int dx = 0; dx < 3; ++dx) {
                xv[dy * 3 + dx] = lxc[dy * 18 + dx];
            }
        }
        const float4* wr = reinterpret_cast<const float4*>(&lw[c * 288]);
        #pragma unroll
        for (int p = 0; p < 9; ++p) {
            float xs = xv[p];
            #pragma unroll
            for (int o4 = 0; o4 < 8; ++o4) {
                float4 w4 = wr[p * 8 + o4];
                acc[o4 * 4 + 0] = fmaf(xs, w4.x, acc[o4 * 4 + 0]);
                acc[o4 * 4 + 1] = fmaf(xs, w4.y, acc[o4 * 4 + 1]);
                acc[o4 * 4 + 2] = fmaf(xs, w4.z, acc[o4 * 4 + 2]);
                acc[o4 * 4 + 3] = fmaf(xs, w4.w, acc[o4 * 4 + 3]);
            }
        }
    }

    // BN + ReLU
    #pragma unroll
    for (int o = 0; o < 32; ++o)
        acc[o] = fmaxf(fmaf(acc[o], lA[o], lB[o]), 0.0f);

    // Head: hfeat[o] = relu(sum_c w1[o,c]*x + b1[o]); y = sum_o w2[o]*hfeat + b2
    float y = lhead[136];
    #pragma unroll
    for (int o = 0; o < 4; ++o) {
        float hv = lhead[132 + o];
        #pragma unroll
        for (int cch = 0; cch < 32; ++cch)
            hv = fmaf(lhead[o * 32 + cch], acc[cch], hv);
        hv = fmaxf(hv, 0.0f);
        y = fmaf(lhead[128 + o], hv, y);
    }
    float sig = 1.0f / (1.0f + __expf(-y));
    sig_out[(n << 14) + ((h0 + ty) << 7) + (w0 + tx)] = sig;
}

__global__ __launch_bounds__(256) void smooth_kernel(
    const float* __restrict__ sig,      // (32,128,128)
    const float* __restrict__ masks,    // (32,128,128)
    const float* __restrict__ sw,       // (1,2,5,5)
    const float* __restrict__ sb,       // (1)
    float* __restrict__ out)            // (32,128,128)
{
    __shared__ float ls[2][400];   // 20x20 halo-2 tiles: sigmoid ch, mask ch

    const int tid  = threadIdx.x;
    const int n    = blockIdx.x >> 6;
    const int tile = blockIdx.x & 63;
    const int h0   = (tile >> 3) << 4;
    const int w0   = (tile & 7) << 4;

    for (int i = tid; i < 800; i += 256) {
        int ch = (i >= 400) ? 1 : 0;
        int r  = i - ch * 400;
        int yy = r / 20;
        int xx = r - yy * 20;
        int h  = h0 + yy - 2;
        int w  = w0 + xx - 2;
        float v = 0.0f;
        if ((unsigned)h < 128u && (unsigned)w < 128u) {
            const float* src = ch ? masks : sig;
            v = src[(n << 14) + (h << 7) + w];
        }
        ls[ch][r] = v;
    }
    __syncthreads();

    const int tx = tid & 15;
    const int ty = tid >> 4;

    float accv = sb[0];
    #pragma unroll
    for (int ch = 0; ch < 2; ++ch) {
        #pragma unroll
        for (int dy = 0; dy < 5; ++dy) {
            #pragma unroll
            for (int dx = 0; dx < 5; ++dx) {
                accv = fmaf(ls[ch][(ty + dy) * 20 + tx + dx],
                            sw[(ch * 5 + dy) * 5 + dx], accv);
            }
        }
    }
    out[(n << 14) + ((h0 + ty) << 7) + (w0 + tx)] = accv;
}

extern "C" void kernel_launch(void* const* d_in, const int* in_sizes, int n_in,
                              void* d_out, int out_size, void* d_ws, size_t ws_size,
                              hipStream_t stream) {
    const float* emb     = (const float*)d_in[0];
    const float* inc     = (const float*)d_in[1];
    const float* masks   = (const float*)d_in[2];
    const float* conv_w  = (const float*)d_in[3];
    const float* conv_b  = (const float*)d_in[4];
    const float* bn_g    = (const float*)d_in[5];
    const float* bn_b    = (const float*)d_in[6];
    const float* bn_m    = (const float*)d_in[7];
    const float* bn_v    = (const float*)d_in[8];
    const float* sw      = (const float*)d_in[9];
    const float* sb      = (const float*)d_in[10];
    float* out = (float*)d_out;
    float* sig = (float*)d_ws;   // 32*128*128 f32 = 2 MB scratch

    fused_main_kernel<<<2048, 256, 0, stream>>>(emb, inc, conv_w, conv_b,
                                                bn_g, bn_b, bn_m, bn_v, sig);
    smooth_kernel<<<2048, 256, 0, stream>>>(sig, masks, sw, sb, out);
}

// Round 2
// 232.445 us; speedup vs baseline: 1.6388x; 1.6388x over previous
//
#include <hip/hip_runtime.h>

// embedding: (32, 512, 32, 32) f32 ; pixel_shuffle r=4 -> x_ps (32, 32, 128, 128)
// conv 3x3 pad1 (32->32) + BN + ReLU ; head: 32->4 relu -> 1 ; sigmoid
// concat [sig, mask] -> 5x5 conv pad2 (2->1) ; out (32,1,128,128) f32
//
// v2: full-width band tiles (128 x 4 rows), c-chunked LDS staging (8 c/chunk),
//     weights + head + BN via wave-uniform global reads (-> s_load, no LDS),
//     scatter-on-write pixel shuffle so LDS reads are stride-1 conflict-free.

#define PITCH 132   // lx row pitch (x in 0..129; 0 and 129 are zero halo cols)

__global__ __launch_bounds__(256, 4) void fused_main_kernel(
    const float* __restrict__ emb,      // (32,512,32,32)
    const float* __restrict__ inc,      // (32,137)
    const float* __restrict__ conv_w,   // (32,32,3,3) OIHW
    const float* __restrict__ conv_b,   // (32)
    const float* __restrict__ bn_gamma,
    const float* __restrict__ bn_beta,
    const float* __restrict__ bn_mean,
    const float* __restrict__ bn_var,
    float* __restrict__ sig_out)        // (32,128,128)
{
    __shared__ float lx[8 * 6 * PITCH];   // 6336 floats = 25.3 KB

    // Chunked XCD swizzle: hw XCD = bid%8 gets a contiguous logical range,
    // so all bands of the same image share one XCD's L2 (halo-row reuse).
    const int bid = blockIdx.x;
    const int lid = (bid & 7) * 128 + (bid >> 3);   // bijective, 1024 blocks
    const int n    = lid >> 5;    // image 0..31
    const int band = lid & 31;    // 4-row band
    const int h0   = band << 2;

    const int tid = threadIdx.x;
    const int w   = tid & 127;    // output column
    const int ry  = tid >> 7;     // 0/1: this thread does rows ry and ry+2

    // Zero the left/right halo columns once (never touched by staging).
    if (tid < 48) {
        int row = tid;            // cl*6 + y
        lx[row * PITCH + 0]   = 0.0f;
        lx[row * PITCH + 129] = 0.0f;
    }

    float acc1[32], acc2[32];
    #pragma unroll
    for (int o = 0; o < 32; ++o) { acc1[o] = 0.0f; acc2[o] = 0.0f; }

    for (int ch = 0; ch < 4; ++ch) {
        __syncthreads();   // previous chunk's compute done (covers halo-zero on ch=0)

        // Stage x_ps chunk: c = ch*8 .. ch*8+7, rows h0-1 .. h0+4, full width.
        // 192 source rows of 32 floats; thread loads 6 float4s, scatters to LDS.
        #pragma unroll
        for (int k = 0; k < 6; ++k) {
            int i   = tid + (k << 8);   // 0..1535 float4 id
            int r   = i >> 3;           // source row 0..191
            int f4  = i & 7;            // float4 within row
            int cl  = r / 24;
            int rem = r - cl * 24;
            int y   = rem >> 2;         // 0..5  (h = h0 + y - 1)
            int sx  = rem & 3;
            int h   = h0 + y - 1;
            float4 v = make_float4(0.f, 0.f, 0.f, 0.f);
            if ((unsigned)h < 128u) {
                int hq = h >> 2;
                int sy = h & 3;
                int cc = ((ch * 8 + cl) << 4) + (sy << 2) + sx;
                v = *reinterpret_cast<const float4*>(
                        &emb[((n * 512 + cc) << 10) + (hq << 5) + (f4 << 2)]);
            }
            // x = 1 + wq*4 + sx, wq = f4*4 + e
            int base = (cl * 6 + y) * PITCH + 1 + sx + (f4 << 4);
            lx[base + 0]  = v.x;
            lx[base + 4]  = v.y;
            lx[base + 8]  = v.z;
            lx[base + 12] = v.w;
        }
        __syncthreads();

        // Compute: 8 channels, 2 px/thread (rows ry, ry+2), weights via s_load.
        for (int cl = 0; cl < 8; ++cl) {
            const float* xc = &lx[cl * 6 * PITCH];
            float xv[5][3];
            #pragma unroll
            for (int yy = 0; yy < 5; ++yy)
                #pragma unroll
                for (int xx = 0; xx < 3; ++xx)
                    xv[yy][xx] = xc[(ry + yy) * PITCH + w + xx];

            const float* wc = conv_w + (ch * 8 + cl) * 9;   // + oc*288 + p
            #pragma unroll
            for (int p = 0; p < 9; ++p) {
                const int dy = p / 3, dx = p % 3;
                const float a1 = xv[dy][dx];
                const float a2 = xv[dy + 2][dx];
                #pragma unroll
                for (int oc = 0; oc < 32; ++oc) {
                    float wv = wc[oc * 288 + p];   // wave-uniform -> SGPR
                    acc1[oc] = fmaf(a1, wv, acc1[oc]);
                    acc2[oc] = fmaf(a2, wv, acc2[oc]);
                }
            }
        }
    }

    // Epilogue: BN fold + ReLU + 2-layer head + sigmoid. All params uniform.
    const float* hd = inc + n * 137;
    float y1 = hd[136];
    float y2 = hd[136];
    float bn1[32];
    #pragma unroll
    for (int oc = 0; oc < 32; ++oc) {
        float sc = bn_gamma[oc] * rsqrtf(bn_var[oc] + 1e-5f);
        float sh = (conv_b[oc] - bn_mean[oc]) * sc + bn_beta[oc];
        acc1[oc] = fmaxf(fmaf(acc1[oc], sc, sh), 0.0f);
        acc2[oc] = fmaxf(fmaf(acc2[oc], sc, sh), 0.0f);
        bn1[oc] = sc; // keep compiler from folding oddly; unused after
    }
    (void)bn1;
    #pragma unroll
    for (int o = 0; o < 4; ++o) {
        float h1 = hd[132 + o];
        float h2 = h1;
        #pragma unroll
        for (int c = 0; c < 32; ++c) {
            float wv = hd[o * 32 + c];
            h1 = fmaf(wv, acc1[c], h1);
            h2 = fmaf(wv, acc2[c], h2);
        }
        h1 = fmaxf(h1, 0.0f);
        h2 = fmaxf(h2, 0.0f);
        float w2 = hd[128 + o];
        y1 = fmaf(w2, h1, y1);
        y2 = fmaf(w2, h2, y2);
    }
    float s1 = 1.0f / (1.0f + __expf(-y1));
    float s2 = 1.0f / (1.0f + __expf(-y2));
    sig_out[(n << 14) + ((h0 + ry) << 7) + w]     = s1;
    sig_out[(n << 14) + ((h0 + ry + 2) << 7) + w] = s2;
}

__global__ __launch_bounds__(256) void smooth_kernel(
    const float* __restrict__ sig,      // (32,128,128)
    const float* __restrict__ masks,    // (32,128,128)
    const float* __restrict__ sw,       // (1,2,5,5)
    const float* __restrict__ sb,       // (1)
    float* __restrict__ out)            // (32,128,128)
{
    __shared__ float ls[2][400];   // 20x20 halo-2 tiles

    const int tid  = threadIdx.x;
    const int n    = blockIdx.x >> 6;
    const int tile = blockIdx.x & 63;
    const int h0   = (tile >> 3) << 4;
    const int w0   = (tile & 7) << 4;

    for (int i = tid; i < 800; i += 256) {
        int chn = (i >= 400) ? 1 : 0;
        int r  = i - chn * 400;
        int yy = r / 20;
        int xx = r - yy * 20;
        int h  = h0 + yy - 2;
        int w  = w0 + xx - 2;
        float v = 0.0f;
        if ((unsigned)h < 128u && (unsigned)w < 128u) {
            const float* src = chn ? masks : sig;
            v = src[(n << 14) + (h << 7) + w];
        }
        ls[chn][r] = v;
    }
    __syncthreads();

    const int tx = tid & 15;
    const int ty = tid >> 4;

    float accv = sb[0];
    #pragma unroll
    for (int chn = 0; chn < 2; ++chn) {
        #pragma unroll
        for (int dy = 0; dy < 5; ++dy) {
            #pragma unroll
            for (int dx = 0; dx < 5; ++dx) {
                accv = fmaf(ls[chn][(ty + dy) * 20 + tx + dx],
                            sw[(chn * 5 + dy) * 5 + dx], accv);
            }
        }
    }
    out[(n << 14) + ((h0 + ty) << 7) + (w0 + tx)] = accv;
}

extern "C" void kernel_launch(void* const* d_in, const int* in_sizes, int n_in,
                              void* d_out, int out_size, void* d_ws, size_t ws_size,
                              hipStream_t stream) {
    const float* emb     = (const float*)d_in[0];
    const float* inc     = (const float*)d_in[1];
    const float* masks   = (const float*)d_in[2];
    const float* conv_w  = (const float*)d_in[3];
    const float* conv_b  = (const float*)d_in[4];
    const float* bn_g    = (const float*)d_in[5];
    const float* bn_b    = (const float*)d_in[6];
    const float* bn_m    = (const float*)d_in[7];
    const float* bn_v    = (const float*)d_in[8];
    const float* sw      = (const float*)d_in[9];
    const float* sb      = (const float*)d_in[10];
    float* out = (float*)d_out;
    float* sig = (float*)d_ws;   // 32*128*128 f32 = 2 MB scratch

    fused_main_kernel<<<1024, 256, 0, stream>>>(emb, inc, conv_w, conv_b,
                                                bn_g, bn_b, bn_m, bn_v, sig);
    smooth_kernel<<<2048, 256, 0, stream>>>(sig, masks, sw, sb, out);
}

// Round 3
// 133.137 us; speedup vs baseline: 2.8611x; 1.7459x over previous
//
#include <hip/hip_runtime.h>

// embedding: (32, 512, 32, 32) f32 ; pixel_shuffle r=4 -> x_ps (32, 32, 128, 128)
// conv 3x3 pad1 (32->32) + BN + ReLU ; head: 32->4 relu -> 1 ; sigmoid
// concat [sig, mask] -> 5x5 conv pad2 (2->1) ; out (32,1,128,128) f32
//
// v3: 1 px/thread (kills AGPR-shuffle register pressure), weights
//     pre-transposed to [c][p][oc] so each (c,p) is 2x s_load_dwordx16,
//     2-row full-width bands, PITCH=133 to cut staging bank conflicts.

#define PITCH 133   // odd mod 32: scatter writes spread over 16 banks

__global__ void prep_kernel(const float* __restrict__ conv_w,
                            float* __restrict__ wT) {
    int t = blockIdx.x * 256 + threadIdx.x;   // 9216 total
    if (t < 9216) {
        int oc = t & 31;
        int p  = (t >> 5) % 9;
        int c  = t / 288;
        wT[t] = conv_w[oc * 288 + c * 9 + p];   // wT[c][p][oc]
    }
}

__global__ __launch_bounds__(256, 4) void fused_main_kernel(
    const float* __restrict__ emb,      // (32,512,32,32)
    const float* __restrict__ inc,      // (32,137)
    const float* __restrict__ wT,       // (32c,9p,32oc) transposed weights
    const float* __restrict__ conv_b,
    const float* __restrict__ bn_gamma,
    const float* __restrict__ bn_beta,
    const float* __restrict__ bn_mean,
    const float* __restrict__ bn_var,
    float* __restrict__ sig_out)        // (32,128,128)
{
    __shared__ float lx[32 * PITCH];    // 8c x 4rows x PITCH = 17.0 KB

    // Chunked XCD swizzle (bijective: 2048 = 8*256): all bands of an image
    // land on one XCD -> halo-row L2 reuse.
    const int bid = blockIdx.x;
    const int lid = (bid & 7) * 256 + (bid >> 3);
    const int n    = lid >> 6;    // image 0..31
    const int band = lid & 63;    // 2-row band
    const int h0   = band << 1;

    const int tid = threadIdx.x;
    const int w   = tid & 127;    // output column
    const int ry  = tid >> 7;     // 0/1

    // Zero halo columns x=0 and x=129 (written nowhere in staging).
    if (tid < 64) {
        int rr = tid >> 1;
        lx[rr * PITCH + ((tid & 1) ? 129 : 0)] = 0.0f;
    }

    float acc[32];
    #pragma unroll
    for (int o = 0; o < 32; ++o) acc[o] = 0.0f;

    for (int ch = 0; ch < 4; ++ch) {
        __syncthreads();   // prev chunk compute done (covers halo-zero at ch=0)

        // Stage 8 channels x 4 x_ps rows (h0-1 .. h0+2), full width.
        // 128 source rows of 32 floats = 1024 float4, 4 per thread.
        #pragma unroll
        for (int k = 0; k < 4; ++k) {
            int i  = tid + (k << 8);    // 0..1023
            int f4 = i & 7;
            int r  = i >> 3;            // cl*16 + y*4 + sx
            int sx = r & 3;
            int y  = (r >> 2) & 3;
            int cl = r >> 4;
            int h  = h0 + y - 1;
            float4 v = make_float4(0.f, 0.f, 0.f, 0.f);
            if ((unsigned)h < 128u) {
                int cc = ((ch * 8 + cl) << 4) + ((h & 3) << 2) + sx;
                v = *reinterpret_cast<const float4*>(
                        &emb[((n * 512 + cc) << 10) + ((h >> 2) << 5) + (f4 << 2)]);
            }
            int base = (cl * 4 + y) * PITCH + 1 + sx + (f4 << 4);
            lx[base + 0]  = v.x;
            lx[base + 4]  = v.y;
            lx[base + 8]  = v.z;
            lx[base + 12] = v.w;
        }
        __syncthreads();

        // Compute: 8 channels, 1 px/thread, weights via merged s_load_dwordx16.
        #pragma unroll 2
        for (int cl = 0; cl < 8; ++cl) {
            const float* xc = &lx[(cl * 4 + ry) * PITCH + w];
            float xv[3][3];
            #pragma unroll
            for (int yy = 0; yy < 3; ++yy)
                #pragma unroll
                for (int xx = 0; xx < 3; ++xx)
                    xv[yy][xx] = xc[yy * PITCH + xx];

            const float* wp = wT + (ch * 8 + cl) * 288;   // [p][oc]
            #pragma unroll
            for (int p = 0; p < 9; ++p) {
                const float a = xv[p / 3][p % 3];
                #pragma unroll
                for (int oc = 0; oc < 32; ++oc)
                    acc[oc] = fmaf(a, wp[p * 32 + oc], acc[oc]);
            }
        }
    }

    // Epilogue: BN fold + ReLU + head + sigmoid (all params wave-uniform).
    const float* hd = inc + n * 137;
    #pragma unroll
    for (int oc = 0; oc < 32; ++oc) {
        float sc = bn_gamma[oc] * rsqrtf(bn_var[oc] + 1e-5f);
        float sh = (conv_b[oc] - bn_mean[oc]) * sc + bn_beta[oc];
        acc[oc] = fmaxf(fmaf(acc[oc], sc, sh), 0.0f);
    }
    float y = hd[136];
    #pragma unroll
    for (int o = 0; o < 4; ++o) {
        float hv = hd[132 + o];
        #pragma unroll
        for (int c = 0; c < 32; ++c)
            hv = fmaf(hd[o * 32 + c], acc[c], hv);
        hv = fmaxf(hv, 0.0f);
        y = fmaf(hd[128 + o], hv, y);
    }
    float s = 1.0f / (1.0f + __expf(-y));
    sig_out[(n << 14) + ((h0 + ry) << 7) + w] = s;
}

__global__ __launch_bounds__(256) void smooth_kernel(
    const float* __restrict__ sig,      // (32,128,128)
    const float* __restrict__ masks,    // (32,128,128)
    const float* __restrict__ sw,       // (1,2,5,5)
    const float* __restrict__ sb,       // (1)
    float* __restrict__ out)            // (32,128,128)
{
    __shared__ float ls[2][400];   // 20x20 halo-2 tiles

    const int tid  = threadIdx.x;
    const int n    = blockIdx.x >> 6;
    const int tile = blockIdx.x & 63;
    const int h0   = (tile >> 3) << 4;
    const int w0   = (tile & 7) << 4;

    for (int i = tid; i < 800; i += 256) {
        int chn = (i >= 400) ? 1 : 0;
        int r  = i - chn * 400;
        int yy = r / 20;
        int xx = r - yy * 20;
        int h  = h0 + yy - 2;
        int w  = w0 + xx - 2;
        float v = 0.0f;
        if ((unsigned)h < 128u && (unsigned)w < 128u) {
            const float* src = chn ? masks : sig;
            v = src[(n << 14) + (h << 7) + w];
        }
        ls[chn][r] = v;
    }
    __syncthreads();

    const int tx = tid & 15;
    const int ty = tid >> 4;

    float accv = sb[0];
    #pragma unroll
    for (int chn = 0; chn < 2; ++chn) {
        #pragma unroll
        for (int dy = 0; dy < 5; ++dy) {
            #pragma unroll
            for (int dx = 0; dx < 5; ++dx) {
                accv = fmaf(ls[chn][(ty + dy) * 20 + tx + dx],
                            sw[(chn * 5 + dy) * 5 + dx], accv);
            }
        }
    }
    out[(n << 14) + ((h0 + ty) << 7) + (w0 + tx)] = accv;
}

extern "C" void kernel_launch(void* const* d_in, const int* in_sizes, int n_in,
                              void* d_out, int out_size, void* d_ws, size_t ws_size,
                              hipStream_t stream) {
    const float* emb     = (const float*)d_in[0];
    const float* inc     = (const float*)d_in[1];
    const float* masks   = (const float*)d_in[2];
    const float* conv_w  = (const float*)d_in[3];
    const float* conv_b  = (const float*)d_in[4];
    const float* bn_g    = (const float*)d_in[5];
    const float* bn_b    = (const float*)d_in[6];
    const float* bn_m    = (const float*)d_in[7];
    const float* bn_v    = (const float*)d_in[8];
    const float* sw      = (const float*)d_in[9];
    const float* sb      = (const float*)d_in[10];
    float* out = (float*)d_out;
    float* sig = (float*)d_ws;                    // 2 MB
    float* wT  = (float*)d_ws + 32 * 128 * 128;   // + 36 KB transposed weights

    prep_kernel<<<36, 256, 0, stream>>>(conv_w, wT);
    fused_main_kernel<<<2048, 256, 0, stream>>>(emb, inc, wT, conv_b,
                                                bn_g, bn_b, bn_m, bn_v, sig);
    smooth_kernel<<<2048, 256, 0, stream>>>(sig, masks, sw, sb, out);
}

// Round 4
// 40.022 us; speedup vs baseline: 9.5178x; 3.3266x over previous
//
#include <hip/hip_runtime.h>

// embedding: (32, 512, 32, 32) f32 ; pixel_shuffle r=4 -> x_ps (32, 32, 128, 128)
// conv 3x3 pad1 (32->32) + BN + ReLU ; head: 32->4 relu -> 1 ; sigmoid
// concat [sig, mask] -> 5x5 conv pad2 (2->1) ; out (32,1,128,128) f32
//
// v4: bf16 MFMA implicit-GEMM conv (16x16x32), k-slot bijection k=(p=kk,
//     c=g*8+j) so each A-fragment is ONE swizzled ds_read_b128 from an
//     [y][x][c] LDS tile; B fragments pre-packed by prep kernel; epilogue
//     bounces BN+ReLU'd conv out through LDS [oc][px] -> per-pixel head.

typedef __attribute__((ext_vector_type(8))) short short8;
typedef __attribute__((ext_vector_type(4))) float f32x4;

static __device__ __forceinline__ ushort f2bf(float x) {
    union { float f; uint u; } v; v.f = x;
    uint r = v.u + 0x7fffu + ((v.u >> 16) & 1u);   // round-nearest-even
    return (ushort)(r >> 16);
}
static __device__ __forceinline__ float bf2f(ushort u) {
    union { uint u; float f; } v; v.u = ((uint)u) << 16; return v.f;
}

#define SIG_ELEMS (32 * 128 * 128)
#define BFRAG_OFF (SIG_ELEMS * 4)            // bytes into d_ws
#define SC_OFF    (BFRAG_OFF + 18432)
#define SH_OFF    (SC_OFF + 128)

// ---- prep: pack B fragments (bf16) + fold BN into sc/sh tables ----
__global__ void prep_kernel(const float* __restrict__ conv_w,
                            const float* __restrict__ conv_b,
                            const float* __restrict__ bn_gamma,
                            const float* __restrict__ bn_beta,
                            const float* __restrict__ bn_mean,
                            const float* __restrict__ bn_var,
                            ushort* __restrict__ bfrag,   // [18][64][8]
                            float* __restrict__ scb, float* __restrict__ shb) {
    int t = blockIdx.x * 256 + threadIdx.x;
    if (t < 9216) {
        int j    = t & 7;
        int lane = (t >> 3) & 63;
        int knt  = t >> 9;          // 0..17 = kk*2 + nt
        int kk   = knt >> 1;        // tap p
        int nt   = knt & 1;
        int oc   = (lane & 15) + nt * 16;
        int c    = (lane >> 4) * 8 + j;
        bfrag[t] = f2bf(conv_w[oc * 288 + c * 9 + kk]);
    } else if (t < 9248) {
        int oc = t - 9216;
        float sc = bn_gamma[oc] * rsqrtf(bn_var[oc] + 1e-5f);
        scb[oc] = sc;
        shb[oc] = (conv_b[oc] - bn_mean[oc]) * sc + bn_beta[oc];
    }
}

// ---- main: implicit-GEMM conv + BN + ReLU + head + sigmoid ----
#define PITCHB 8320          // 130 cells * 64 B per staged row
#define BPITCH 258           // [oc][px] bounce pitch in ushort (516 B, odd words)

__global__ __launch_bounds__(256, 4) void fused_main_kernel(
    const float* __restrict__ emb,      // (32,512,32,32)
    const float* __restrict__ inc,      // (32,137)
    const ushort* __restrict__ bfrag,   // [18][64][8] bf16
    const float* __restrict__ scb,
    const float* __restrict__ shb,
    float* __restrict__ sig_out)        // (32,128,128)
{
    __shared__ __align__(16) char smem[4 * PITCHB];   // 33280 B

    const int bid = blockIdx.x;
    const int lid = (bid & 7) * 256 + (bid >> 3);     // XCD swizzle (2048=8*256)
    const int n    = lid >> 6;     // image
    const int band = lid & 63;     // 2-row band
    const int h0   = band << 1;

    const int tid  = threadIdx.x;
    const int lane = tid & 63;
    const int wv   = tid >> 6;
    const int g    = lane >> 4;    // c_high / C-row group
    const int m    = lane & 15;    // A row (pixel) / C col (oc)
    const int rw   = wv >> 1;      // this wave's output row (0/1)
    const int xq   = (wv & 1) * 64;

    // Zero halo cells xi=0 and xi=129 (16 u32 each, 4 rows x 2 cols).
    if (tid < 128) {
        int y   = tid >> 5;
        int col = (tid >> 4) & 1;
        int wrd = tid & 15;
        ((uint*)smem)[(y * PITCHB + (col ? 129 : 0) * 64) / 4 + wrd] = 0u;
    }

    // Stage x_ps rows h0-1..h0+2, all 32 channels, bf16 pairs, swizzled.
    #pragma unroll
    for (int k = 0; k < 8; ++k) {
        int u  = tid + (k << 8);       // 0..2047
        int f  = u & 7;                // float4 index in source row
        int sx = (u >> 3) & 3;
        int cp = (u >> 5) & 15;        // channel pair: c = 2cp, 2cp+1
        int y  = u >> 9;               // staged row
        int h  = h0 + y - 1;
        float4 v0 = make_float4(0.f, 0.f, 0.f, 0.f);
        float4 v1 = v0;
        if ((unsigned)h < 128u) {
            int cc0  = cp * 32 + ((h & 3) << 2) + sx;
            long base = ((long)(n * 512 + cc0) << 10) + ((h >> 2) << 5) + (f << 2);
            v0 = *reinterpret_cast<const float4*>(&emb[base]);
            v1 = *reinterpret_cast<const float4*>(&emb[base + (16 << 10)]);
        }
        const float e0[4] = {v0.x, v0.y, v0.z, v0.w};
        const float e1[4] = {v1.x, v1.y, v1.z, v1.w};
        #pragma unroll
        for (int e = 0; e < 4; ++e) {
            int xi   = 1 + sx + (f << 4) + (e << 2);   // staged col 1..128
            int slot = ((cp >> 2) ^ ((xi >> 1) ^ (xi >> 4))) & 3;
            uint pk  = ((uint)f2bf(e1[e]) << 16) | (uint)f2bf(e0[e]);
            ((uint*)smem)[(y * PITCHB + xi * 64 + (slot << 4) + ((cp & 3) << 2)) / 4] = pk;
        }
    }
    __syncthreads();

    // Precompute A-fragment addresses: 4 tiles x 3 dx.
    int adr[4][3];
    #pragma unroll
    for (int t = 0; t < 4; ++t)
        #pragma unroll
        for (int dx = 0; dx < 3; ++dx) {
            int xi = xq + t * 16 + m + dx;   // = image x +1 already (x0+m+dx-1+1)
            int slot = (g ^ ((xi >> 1) ^ (xi >> 4))) & 3;
            adr[t][dx] = rw * PITCHB + xi * 64 + (slot << 4);
        }

    f32x4 acc[4][2];
    #pragma unroll
    for (int t = 0; t < 4; ++t)
        #pragma unroll
        for (int nt = 0; nt < 2; ++nt)
            acc[t][nt] = (f32x4){0.f, 0.f, 0.f, 0.f};

    #pragma unroll
    for (int kk = 0; kk < 9; ++kk) {
        const int dy = kk / 3, dxs = kk % 3;
        short8 b0 = *reinterpret_cast<const short8*>(bfrag + (((kk * 2 + 0) * 64 + lane) << 3));
        short8 b1 = *reinterpret_cast<const short8*>(bfrag + (((kk * 2 + 1) * 64 + lane) << 3));
        #pragma unroll
        for (int t = 0; t < 4; ++t) {
            short8 a = *reinterpret_cast<const short8*>(&smem[adr[t][dxs] + dy * PITCHB]);
            acc[t][0] = __builtin_amdgcn_mfma_f32_16x16x32_bf16(a, b0, acc[t][0], 0, 0, 0);
            acc[t][1] = __builtin_amdgcn_mfma_f32_16x16x32_bf16(a, b1, acc[t][1], 0, 0, 0);
        }
    }

    // Epilogue 1: BN + ReLU, bounce to LDS as [oc][px] bf16 (pitch 258 u16).
    __syncthreads();   // everyone done reading lx
    {
        float sc0 = scb[m],      sh0 = shb[m];
        float sc1 = scb[m + 16], sh1 = shb[m + 16];
        uint* lb32 = (uint*)smem;
        #pragma unroll
        for (int t = 0; t < 4; ++t) {
            int pxb = rw * 128 + xq + t * 16 + g * 4;   // multiple of 4
            #pragma unroll
            for (int nt = 0; nt < 2; ++nt) {
                int oc = nt * 16 + m;
                float sc = nt ? sc1 : sc0, sh = nt ? sh1 : sh0;
                f32x4 A = acc[t][nt];
                float r0 = fmaxf(fmaf(A.x, sc, sh), 0.f);
                float r1 = fmaxf(fmaf(A.y, sc, sh), 0.f);
                float r2 = fmaxf(fmaf(A.z, sc, sh), 0.f);
                float r3 = fmaxf(fmaf(A.w, sc, sh), 0.f);
                int wbase = (oc * BPITCH + pxb) >> 1;
                lb32[wbase]     = ((uint)f2bf(r1) << 16) | (uint)f2bf(r0);
                lb32[wbase + 1] = ((uint)f2bf(r3) << 16) | (uint)f2bf(r2);
            }
        }
    }
    __syncthreads();

    // Epilogue 2: per-pixel head (1 thread = 1 pixel), fp32, sigmoid.
    {
        const ushort* lb = (const ushort*)smem;
        int px  = tid;
        int row = px >> 7, x = px & 127;
        float xv[32];
        #pragma unroll
        for (int c = 0; c < 32; ++c)
            xv[c] = bf2f(lb[c * BPITCH + px]);

        const float* hd = inc + n * 137;
        float y = hd[136];
        #pragma unroll
        for (int o = 0; o < 4; ++o) {
            float hv = hd[132 + o];
            #pragma unroll
            for (int c = 0; c < 32; ++c)
                hv = fmaf(hd[o * 32 + c], xv[c], hv);
            hv = fmaxf(hv, 0.0f);
            y = fmaf(hd[128 + o], hv, y);
        }
        float s = 1.0f / (1.0f + __expf(-y));
        sig_out[(n << 14) + ((h0 + row) << 7) + x] = s;
    }
}

// ---- smooth: 5x5, 2ch -> 1ch ----
__global__ __launch_bounds__(256) void smooth_kernel(
    const float* __restrict__ sig,
    const float* __restrict__ masks,
    const float* __restrict__ sw,
    const float* __restrict__ sb,
    float* __restrict__ out)
{
    __shared__ float ls[2][400];

    const int tid  = threadIdx.x;
    const int n    = blockIdx.x >> 6;
    const int tile = blockIdx.x & 63;
    const int h0   = (tile >> 3) << 4;
    const int w0   = (tile & 7) << 4;

    for (int i = tid; i < 800; i += 256) {
        int chn = (i >= 400) ? 1 : 0;
        int r  = i - chn * 400;
        int yy = r / 20;
        int xx = r - yy * 20;
        int h  = h0 + yy - 2;
        int w  = w0 + xx - 2;
        float v = 0.0f;
        if ((unsigned)h < 128u && (unsigned)w < 128u) {
            const float* src = chn ? masks : sig;
            v = src[(n << 14) + (h << 7) + w];
        }
        ls[chn][r] = v;
    }
    __syncthreads();

    const int tx = tid & 15;
    const int ty = tid >> 4;

    float accv = sb[0];
    #pragma unroll
    for (int chn = 0; chn < 2; ++chn)
        #pragma unroll
        for (int dy = 0; dy < 5; ++dy)
            #pragma unroll
            for (int dx = 0; dx < 5; ++dx)
                accv = fmaf(ls[chn][(ty + dy) * 20 + tx + dx],
                            sw[(chn * 5 + dy) * 5 + dx], accv);
    out[(n << 14) + ((h0 + ty) << 7) + (w0 + tx)] = accv;
}

extern "C" void kernel_launch(void* const* d_in, const int* in_sizes, int n_in,
                              void* d_out, int out_size, void* d_ws, size_t ws_size,
                              hipStream_t stream) {
    const float* emb     = (const float*)d_in[0];
    const float* inc     = (const float*)d_in[1];
    const float* masks   = (const float*)d_in[2];
    const float* conv_w  = (const float*)d_in[3];
    const float* conv_b  = (const float*)d_in[4];
    const float* bn_g    = (const float*)d_in[5];
    const float* bn_b    = (const float*)d_in[6];
    const float* bn_m    = (const float*)d_in[7];
    const float* bn_v    = (const float*)d_in[8];
    const float* sw      = (const float*)d_in[9];
    const float* sb      = (const float*)d_in[10];
    float*  out   = (float*)d_out;
    float*  sig   = (float*)d_ws;
    ushort* bfrag = (ushort*)((char*)d_ws + BFRAG_OFF);
    float*  scb   = (float*)((char*)d_ws + SC_OFF);
    float*  shb   = (float*)((char*)d_ws + SH_OFF);

    prep_kernel<<<37, 256, 0, stream>>>(conv_w, conv_b, bn_g, bn_b, bn_m, bn_v,
                                        bfrag, scb, shb);
    fused_main_kernel<<<2048, 256, 0, stream>>>(emb, inc, bfrag, scb, shb, sig);
    smooth_kernel<<<2048, 256, 0, stream>>>(sig, masks, sw, sb, out);
}

// Round 5
// 37.986 us; speedup vs baseline: 10.0279x; 1.0536x over previous
//
#include <hip/hip_runtime.h>

// embedding: (32, 512, 32, 32) f32 ; pixel_shuffle r=4 -> x_ps (32, 32, 128, 128)
// conv 3x3 pad1 (32->32) + BN + ReLU ; head: 32->4 relu -> 1 ; sigmoid
// concat [sig, mask] -> 5x5 conv pad2 (2->1) ; out (32,1,128,128) f32
//
// v5: v4 MFMA implicit-GEMM core +
//   - staging split into load-all(16 dwordx4)->convert phases (MLP latency hide)
//   - v_cvt_pk_bf16_f32 for f32->bf16 pair packing (1 VALU op per pair)
//   - epilogue bounce in fp32 [px][36] (16B-aligned rows, b128 head reads)

typedef __attribute__((ext_vector_type(8))) short short8;
typedef __attribute__((ext_vector_type(4))) float f32x4;

static __device__ __forceinline__ ushort f2bf(float x) {
    union { float f; uint u; } v; v.f = x;
    uint r = v.u + 0x7fffu + ((v.u >> 16) & 1u);   // round-nearest-even
    return (ushort)(r >> 16);
}
static __device__ __forceinline__ uint cvt_pk_bf16(float lo, float hi) {
    uint r;
    asm("v_cvt_pk_bf16_f32 %0, %1, %2" : "=v"(r) : "v"(lo), "v"(hi));
    return r;   // {hi=bf16(hi), lo=bf16(lo)}
}

#define SIG_ELEMS (32 * 128 * 128)
#define BFRAG_OFF (SIG_ELEMS * 4)            // bytes into d_ws
#define SC_OFF    (BFRAG_OFF + 18432)
#define SH_OFF    (SC_OFF + 128)

// ---- prep: pack B fragments (bf16) + fold BN into sc/sh tables ----
__global__ void prep_kernel(const float* __restrict__ conv_w,
                            const float* __restrict__ conv_b,
                            const float* __restrict__ bn_gamma,
                            const float* __restrict__ bn_beta,
                            const float* __restrict__ bn_mean,
                            const float* __restrict__ bn_var,
                            ushort* __restrict__ bfrag,   // [18][64][8]
                            float* __restrict__ scb, float* __restrict__ shb) {
    int t = blockIdx.x * 256 + threadIdx.x;
    if (t < 9216) {
        int j    = t & 7;
        int lane = (t >> 3) & 63;
        int knt  = t >> 9;          // 0..17 = kk*2 + nt
        int kk   = knt >> 1;        // tap p
        int nt   = knt & 1;
        int oc   = (lane & 15) + nt * 16;
        int c    = (lane >> 4) * 8 + j;
        bfrag[t] = f2bf(conv_w[oc * 288 + c * 9 + kk]);
    } else if (t < 9248) {
        int oc = t - 9216;
        float sc = bn_gamma[oc] * rsqrtf(bn_var[oc] + 1e-5f);
        scb[oc] = sc;
        shb[oc] = (conv_b[oc] - bn_mean[oc]) * sc + bn_beta[oc];
    }
}

// ---- main: implicit-GEMM conv + BN + ReLU + head + sigmoid ----
#define PITCHB 8320          // 130 cells * 64 B per staged row
#define HPITCH 36            // fp32 bounce pitch (144 B: 16B-aligned rows)

__global__ __launch_bounds__(256, 4) void fused_main_kernel(
    const float* __restrict__ emb,      // (32,512,32,32)
    const float* __restrict__ inc,      // (32,137)
    const ushort* __restrict__ bfrag,   // [18][64][8] bf16
    const float* __restrict__ scb,
    const float* __restrict__ shb,
    float* __restrict__ sig_out)        // (32,128,128)
{
    __shared__ __align__(16) char smem[256 * HPITCH * 4];   // 36864 B >= 4*PITCHB

    const int bid = blockIdx.x;
    const int lid = (bid & 7) * 256 + (bid >> 3);     // XCD swizzle (2048=8*256)
    const int n    = lid >> 6;     // image
    const int band = lid & 63;     // 2-row band
    const int h0   = band << 1;

    const int tid  = threadIdx.x;
    const int lane = tid & 63;
    const int wv   = tid >> 6;
    const int g    = lane >> 4;    // c_high group
    const int m    = lane & 15;    // A row (pixel) / C col (oc)
    const int rw   = wv >> 1;      // wave's output row (0/1)
    const int xq   = (wv & 1) * 64;

    // Zero halo cells xi=0 and xi=129.
    if (tid < 128) {
        int y   = tid >> 5;
        int col = (tid >> 4) & 1;
        int wrd = tid & 15;
        ((uint*)smem)[(y * PITCHB + (col ? 129 : 0) * 64) / 4 + wrd] = 0u;
    }

    // ---- staging phase A: issue ALL 16 global loads into registers ----
    float4 pre0[8], pre1[8];
    #pragma unroll
    for (int k = 0; k < 8; ++k) {
        int u  = tid + (k << 8);       // 0..2047
        int f  = u & 7;
        int sx = (u >> 3) & 3;
        int cp = (u >> 5) & 15;
        int y  = u >> 9;
        int h  = h0 + y - 1;
        pre0[k] = make_float4(0.f, 0.f, 0.f, 0.f);
        pre1[k] = pre0[k];
        if ((unsigned)h < 128u) {
            int cc0  = cp * 32 + ((h & 3) << 2) + sx;
            long base = ((long)(n * 512 + cc0) << 10) + ((h >> 2) << 5) + (f << 2);
            pre0[k] = *reinterpret_cast<const float4*>(&emb[base]);
            pre1[k] = *reinterpret_cast<const float4*>(&emb[base + (16 << 10)]);
        }
    }
    // ---- staging phase B: convert (cvt_pk) + swizzled scatter to LDS ----
    #pragma unroll
    for (int k = 0; k < 8; ++k) {
        int u  = tid + (k << 8);
        int f  = u & 7;
        int sx = (u >> 3) & 3;
        int cp = (u >> 5) & 15;
        int y  = u >> 9;
        uint pk0 = cvt_pk_bf16(pre0[k].x, pre1[k].x);
        uint pk1 = cvt_pk_bf16(pre0[k].y, pre1[k].y);
        uint pk2 = cvt_pk_bf16(pre0[k].z, pre1[k].z);
        uint pk3 = cvt_pk_bf16(pre0[k].w, pre1[k].w);
        const uint pks[4] = {pk0, pk1, pk2, pk3};
        #pragma unroll
        for (int e = 0; e < 4; ++e) {
            int xi   = 1 + sx + (f << 4) + (e << 2);   // staged col 1..128
            int slot = ((cp >> 2) ^ ((xi >> 1) ^ (xi >> 4))) & 3;
            ((uint*)smem)[(y * PITCHB + xi * 64 + (slot << 4) + ((cp & 3) << 2)) / 4] = pks[e];
        }
    }
    __syncthreads();

    // A-fragment addresses: 4 tiles x 3 dx.
    int adr[4][3];
    #pragma unroll
    for (int t = 0; t < 4; ++t)
        #pragma unroll
        for (int dx = 0; dx < 3; ++dx) {
            int xi = xq + t * 16 + m + dx;
            int slot = (g ^ ((xi >> 1) ^ (xi >> 4))) & 3;
            adr[t][dx] = rw * PITCHB + xi * 64 + (slot << 4);
        }

    f32x4 acc[4][2];
    #pragma unroll
    for (int t = 0; t < 4; ++t)
        #pragma unroll
        for (int nt = 0; nt < 2; ++nt)
            acc[t][nt] = (f32x4){0.f, 0.f, 0.f, 0.f};

    #pragma unroll
    for (int kk = 0; kk < 9; ++kk) {
        const int dy = kk / 3, dxs = kk % 3;
        short8 b0 = *reinterpret_cast<const short8*>(bfrag + (((kk * 2 + 0) * 64 + lane) << 3));
        short8 b1 = *reinterpret_cast<const short8*>(bfrag + (((kk * 2 + 1) * 64 + lane) << 3));
        #pragma unroll
        for (int t = 0; t < 4; ++t) {
            short8 a = *reinterpret_cast<const short8*>(&smem[adr[t][dxs] + dy * PITCHB]);
            acc[t][0] = __builtin_amdgcn_mfma_f32_16x16x32_bf16(a, b0, acc[t][0], 0, 0, 0);
            acc[t][1] = __builtin_amdgcn_mfma_f32_16x16x32_bf16(a, b1, acc[t][1], 0, 0, 0);
        }
    }

    // Epilogue 1: BN + ReLU -> fp32 LDS bounce [px][HPITCH].
    __syncthreads();   // everyone done reading the A tile
    {
        float* lb = (float*)smem;
        float sc0 = scb[m],      sh0 = shb[m];
        float sc1 = scb[m + 16], sh1 = shb[m + 16];
        #pragma unroll
        for (int t = 0; t < 4; ++t) {
            int pxb = rw * 128 + xq + t * 16 + g * 4;
            #pragma unroll
            for (int nt = 0; nt < 2; ++nt) {
                int oc = nt * 16 + m;
                float sc = nt ? sc1 : sc0, sh = nt ? sh1 : sh0;
                f32x4 A = acc[t][nt];
                lb[(pxb + 0) * HPITCH + oc] = fmaxf(fmaf(A.x, sc, sh), 0.f);
                lb[(pxb + 1) * HPITCH + oc] = fmaxf(fmaf(A.y, sc, sh), 0.f);
                lb[(pxb + 2) * HPITCH + oc] = fmaxf(fmaf(A.z, sc, sh), 0.f);
                lb[(pxb + 3) * HPITCH + oc] = fmaxf(fmaf(A.w, sc, sh), 0.f);
            }
        }
    }
    __syncthreads();

    // Epilogue 2: per-pixel head (1 thread = 1 pixel), b128 reads, sigmoid.
    {
        const f32x4* row = reinterpret_cast<const f32x4*>((float*)smem + tid * HPITCH);
        f32x4 xv[8];
        #pragma unroll
        for (int q = 0; q < 8; ++q) xv[q] = row[q];

        const float* hd = inc + n * 137;
        float y = hd[136];
        #pragma unroll
        for (int o = 0; o < 4; ++o) {
            float hv = hd[132 + o];
            #pragma unroll
            for (int q = 0; q < 8; ++q) {
                hv = fmaf(hd[o * 32 + q * 4 + 0], xv[q].x, hv);
                hv = fmaf(hd[o * 32 + q * 4 + 1], xv[q].y, hv);
                hv = fmaf(hd[o * 32 + q * 4 + 2], xv[q].z, hv);
                hv = fmaf(hd[o * 32 + q * 4 + 3], xv[q].w, hv);
            }
            hv = fmaxf(hv, 0.0f);
            y = fmaf(hd[128 + o], hv, y);
        }
        float s = 1.0f / (1.0f + __expf(-y));
        int row_i = tid >> 7, x = tid & 127;
        sig_out[(n << 14) + ((h0 + row_i) << 7) + x] = s;
    }
}

// ---- smooth: 5x5, 2ch -> 1ch ----
__global__ __launch_bounds__(256) void smooth_kernel(
    const float* __restrict__ sig,
    const float* __restrict__ masks,
    const float* __restrict__ sw,
    const float* __restrict__ sb,
    float* __restrict__ out)
{
    __shared__ float ls[2][400];

    const int tid  = threadIdx.x;
    const int n    = blockIdx.x >> 6;
    const int tile = blockIdx.x & 63;
    const int h0   = (tile >> 3) << 4;
    const int w0   = (tile & 7) << 4;

    for (int i = tid; i < 800; i += 256) {
        int chn = (i >= 400) ? 1 : 0;
        int r  = i - chn * 400;
        int yy = r / 20;
        int xx = r - yy * 20;
        int h  = h0 + yy - 2;
        int w  = w0 + xx - 2;
        float v = 0.0f;
        if ((unsigned)h < 128u && (unsigned)w < 128u) {
            const float* src = chn ? masks : sig;
            v = src[(n << 14) + (h << 7) + w];
        }
        ls[chn][r] = v;
    }
    __syncthreads();

    const int tx = tid & 15;
    const int ty = tid >> 4;

    float accv = sb[0];
    #pragma unroll
    for (int chn = 0; chn < 2; ++chn)
        #pragma unroll
        for (int dy = 0; dy < 5; ++dy)
            #pragma unroll
            for (int dx = 0; dx < 5; ++dx)
                accv = fmaf(ls[chn][(ty + dy) * 20 + tx + dx],
                            sw[(chn * 5 + dy) * 5 + dx], accv);
    out[(n << 14) + ((h0 + ty) << 7) + (w0 + tx)] = accv;
}

extern "C" void kernel_launch(void* const* d_in, const int* in_sizes, int n_in,
                              void* d_out, int out_size, void* d_ws, size_t ws_size,
                              hipStream_t stream) {
    const float* emb     = (const float*)d_in[0];
    const float* inc     = (const float*)d_in[1];
    const float* masks   = (const float*)d_in[2];
    const float* conv_w  = (const float*)d_in[3];
    const float* conv_b  = (const float*)d_in[4];
    const float* bn_g    = (const float*)d_in[5];
    const float* bn_b    = (const float*)d_in[6];
    const float* bn_m    = (const float*)d_in[7];
    const float* bn_v    = (const float*)d_in[8];
    const float* sw      = (const float*)d_in[9];
    const float* sb      = (const float*)d_in[10];
    float*  out   = (float*)d_out;
    float*  sig   = (float*)d_ws;
    ushort* bfrag = (ushort*)((char*)d_ws + BFRAG_OFF);
    float*  scb   = (float*)((char*)d_ws + SC_OFF);
    float*  shb   = (float*)((char*)d_ws + SH_OFF);

    prep_kernel<<<37, 256, 0, stream>>>(conv_w, conv_b, bn_g, bn_b, bn_m, bn_v,
                                        bfrag, scb, shb);
    fused_main_kernel<<<2048, 256, 0, stream>>>(emb, inc, bfrag, scb, shb, sig);
    smooth_kernel<<<2048, 256, 0, stream>>>(sig, masks, sw, sb, out);
}